// Round 5
// baseline (245.580 us; speedup 1.0000x reference)
//
#include <hip/hip_runtime.h>
#include <stdint.h>

typedef __bf16 bf16_t;
typedef __bf16 bf16x8 __attribute__((ext_vector_type(8)));
typedef float f32x4 __attribute__((ext_vector_type(4)));

#define LOG2E 1.44269504088896340736f

__device__ __forceinline__ float fexp2(float x) {
#if __has_builtin(__builtin_amdgcn_exp2f)
    return __builtin_amdgcn_exp2f(x);   // bare v_exp_f32
#else
    return exp2f(x);
#endif
}

// ---- async global->LDS, 16B per lane. LDS dest = wave-uniform base + lane*16.
__device__ __forceinline__ void gld_lds16(const bf16_t* g, bf16_t* l) {
    __builtin_amdgcn_global_load_lds(
        (__attribute__((address_space(1))) void*)(bf16_t*)g,
        (__attribute__((address_space(3))) void*)l,
        16, 0, 0);
}

// ============================ fused prep kernel ============================
// blocks [0,8192): x f32->bf16 | [8192,11264): W_qkv transpose | [11264,12288): W_o
__global__ __launch_bounds__(256) void prep_k(
    const float* __restrict__ x, bf16_t* __restrict__ xb,
    const float* __restrict__ Wqkv, bf16_t* __restrict__ wqkvT,
    const float* __restrict__ Wo, bf16_t* __restrict__ woT)
{
    __shared__ float t[32][33];
    const int tid = threadIdx.x;
    int blk = blockIdx.x;
    if (blk < 8192) {
        int i = blk * 1024 + tid * 4;
        float4 v = *(const float4*)(x + i);
        union { bf16_t b[4]; uint2 u; } u;
        u.b[0] = (bf16_t)v.x; u.b[1] = (bf16_t)v.y; u.b[2] = (bf16_t)v.z; u.b[3] = (bf16_t)v.w;
        *(uint2*)(xb + i) = u.u;
        return;
    }
    const float* in; bf16_t* out; int C, bx, by;
    if (blk < 11264) { blk -= 8192; in = Wqkv; out = wqkvT; C = 3072; bx = blk % 96; by = blk / 96; }
    else             { blk -= 11264; in = Wo;   out = woT;   C = 1024; bx = blk % 32; by = blk / 32; }
    const int R = 1024;
    const int tx = tid & 31, ty = tid >> 5;
    const int c0 = bx * 32, r0 = by * 32;
    #pragma unroll
    for (int j = 0; j < 32; j += 8)
        t[ty + j][tx] = in[(size_t)(r0 + ty + j) * C + c0 + tx];
    __syncthreads();
    #pragma unroll
    for (int j = 0; j < 32; j += 8)
        out[(size_t)(c0 + ty + j) * R + r0 + tx] = (bf16_t)t[tx][ty + j];
}

// ================= R2-proven fine-phase pipelined GEMM body =================
// C[128x256] = A[m0:+128,:1024] * B[n0:+256,:1024]^T (row-major, k-contig).
// 512 thr / 8 waves, 2M x 4N, per-wave 64x64. BK=64; K=1024 -> 16 K-tiles.
// 3 LDS slots x (A 16KB + B 32KB) = 144 KB; prefetch distance 2 K-tiles.
// Per K-tile: 2 phases. vmcnt(6) counted wait, never 0 mid-loop.
__device__ __forceinline__ void gemm_body_pipe(
    const bf16_t* __restrict__ A, const bf16_t* __restrict__ Bt,
    bf16_t* Al, bf16_t* Bl, f32x4 (&acc)[4][4], int m0, int n0)
{
    const int tid = threadIdx.x;
    const int w = tid >> 6, lane = tid & 63;
    const int l15 = lane & 15, quad = lane >> 4;
    const int wm = w >> 2, wn = w & 3;

    const int srow = lane >> 3;                 // 0..7 within an 8-row group
    const int scg = ((lane & 7) ^ srow) * 8;    // pre-swizzled global chunk
    const bf16_t* Ag = A  + (size_t)(m0 + w * 16 + srow) * 1024 + scg;
    const bf16_t* Bg = Bt + (size_t)(n0 + w * 32 + srow) * 1024 + scg;

    const int rc0 = (quad ^ (l15 & 7)) * 8;
    const int rc1 = ((quad + 4) ^ (l15 & 7)) * 8;

    auto stage0 = [&](int kt, int ss) {   // A j0, A j1, B j0
        gld_lds16(Ag + kt * 64,                       Al + ss * 8192  + (w * 16) * 64);
        gld_lds16(Ag + kt * 64 + (size_t)8 * 1024,    Al + ss * 8192  + (w * 16 + 8) * 64);
        gld_lds16(Bg + kt * 64,                       Bl + ss * 16384 + (w * 32) * 64);
    };
    auto stage1 = [&](int kt, int ss) {   // B j1, B j2, B j3
        gld_lds16(Bg + kt * 64 + (size_t)8 * 1024,    Bl + ss * 16384 + (w * 32 + 8) * 64);
        gld_lds16(Bg + kt * 64 + (size_t)16 * 1024,   Bl + ss * 16384 + (w * 32 + 16) * 64);
        gld_lds16(Bg + kt * 64 + (size_t)24 * 1024,   Bl + ss * 16384 + (w * 32 + 24) * 64);
    };

    stage0(0, 0); stage1(0, 0);
    stage0(1, 1); stage1(1, 1);
    asm volatile("s_waitcnt vmcnt(6)" ::: "memory");
    __builtin_amdgcn_s_barrier();

    int cs = 0, ss = 2;
    for (int t = 0; t < 16; ++t) {
        const bf16_t* Ab = Al + cs * 8192;
        const bf16_t* Bb = Bl + cs * 16384;
        {
            bf16x8 af[4], bfr[4];
            #pragma unroll
            for (int mi = 0; mi < 4; mi++)
                af[mi] = *(const bf16x8*)(Ab + (wm * 64 + mi * 16 + l15) * 64 + rc0);
            #pragma unroll
            for (int ni = 0; ni < 4; ni++)
                bfr[ni] = *(const bf16x8*)(Bb + (wn * 64 + ni * 16 + l15) * 64 + rc0);
            if (t < 14) stage0(t + 2, ss);
            __builtin_amdgcn_s_barrier();
            __builtin_amdgcn_s_setprio(1);
            #pragma unroll
            for (int mi = 0; mi < 4; mi++)
                #pragma unroll
                for (int ni = 0; ni < 4; ni++)
                    acc[mi][ni] = __builtin_amdgcn_mfma_f32_16x16x32_bf16(
                        af[mi], bfr[ni], acc[mi][ni], 0, 0, 0);
            __builtin_amdgcn_s_setprio(0);
            __builtin_amdgcn_s_barrier();
        }
        {
            bf16x8 af[4], bfr[4];
            #pragma unroll
            for (int mi = 0; mi < 4; mi++)
                af[mi] = *(const bf16x8*)(Ab + (wm * 64 + mi * 16 + l15) * 64 + rc1);
            #pragma unroll
            for (int ni = 0; ni < 4; ni++)
                bfr[ni] = *(const bf16x8*)(Bb + (wn * 64 + ni * 16 + l15) * 64 + rc1);
            if (t < 14) {
                stage1(t + 2, ss);
                asm volatile("s_waitcnt vmcnt(6)" ::: "memory");
            } else if (t == 14) {
                asm volatile("s_waitcnt vmcnt(0)" ::: "memory");
            }
            __builtin_amdgcn_s_barrier();
            __builtin_amdgcn_s_setprio(1);
            #pragma unroll
            for (int mi = 0; mi < 4; mi++)
                #pragma unroll
                for (int ni = 0; ni < 4; ni++)
                    acc[mi][ni] = __builtin_amdgcn_mfma_f32_16x16x32_bf16(
                        af[mi], bfr[ni], acc[mi][ni], 0, 0, 0);
            __builtin_amdgcn_s_setprio(0);
            __builtin_amdgcn_s_barrier();
        }
        cs = (cs == 2) ? 0 : cs + 1;
        ss = (ss == 2) ? 0 : ss + 1;
    }
}

// ============================ GEMM1: qkv projection (A=W, B=x) ============
// grid (32, 24) = 768 blocks. R2-proven version (72.5 us).
__global__ __launch_bounds__(512) void gemm_qkv_k(
    const bf16_t* __restrict__ X, const bf16_t* __restrict__ WT,
    const float* __restrict__ bias,
    bf16_t* __restrict__ Qb, bf16_t* __restrict__ Kb, bf16_t* __restrict__ VTb)
{
    __shared__ bf16_t Al[3 * 128 * 64];   // 48 KB
    __shared__ bf16_t Bl[3 * 256 * 64];   // 96 KB
    const int tid = threadIdx.x;
    const int lane = tid & 63, w = tid >> 6;
    const int l15 = lane & 15, quad = lane >> 4;
    const int wm = w >> 2, wn = w & 3;
    const int n0 = blockIdx.x * 256;   // token rows
    const int m0 = blockIdx.y * 128;   // weight cols

    f32x4 acc[4][4];
    #pragma unroll
    for (int mi = 0; mi < 4; mi++)
        #pragma unroll
        for (int ni = 0; ni < 4; ni++) acc[mi][ni] = (f32x4){0.f, 0.f, 0.f, 0.f};

    gemm_body_pipe(WT, X, Al, Bl, acc, m0, n0);

    const float QSCALE = 0.125f * LOG2E;
    const int region = m0 >> 10;  // 0:Q 1:K 2:V (uniform per block; 128 | 1024)
    #pragma unroll
    for (int mi = 0; mi < 4; mi++) {
        const int mbase = m0 + wm * 64 + mi * 16 + quad * 4;
        const float4 bia = *(const float4*)(bias + mbase);
        const float ba[4] = {bia.x, bia.y, bia.z, bia.w};
        const int col = mbase & 1023;
        const int h = col >> 6, dbase = col & 63;
        #pragma unroll
        for (int ni = 0; ni < 4; ni++) {
            const int n = n0 + wn * 64 + ni * 16 + l15;
            const int b = n >> 11, s = n & 2047;
            if (region == 0) {
                union { bf16_t bv[4]; uint2 u; } u;
                #pragma unroll
                for (int r = 0; r < 4; r++)
                    u.bv[r] = (bf16_t)((acc[mi][ni][r] + ba[r]) * QSCALE);
                *(uint2*)(Qb + (((size_t)b * 16 + h) * 2048 + s) * 64 + dbase) = u.u;
            } else if (region == 1) {
                union { bf16_t bv[4]; uint2 u; } u;
                #pragma unroll
                for (int r = 0; r < 4; r++)
                    u.bv[r] = (bf16_t)(acc[mi][ni][r] + ba[r]);
                *(uint2*)(Kb + (((size_t)b * 16 + h) * 2048 + s) * 64 + dbase) = u.u;
            } else {
                bf16_t* dst = VTb + (((size_t)b * 16 + h) * 64 + dbase) * 2048 + s;
                #pragma unroll
                for (int r = 0; r < 4; r++)
                    dst[(size_t)r * 2048] = (bf16_t)(acc[mi][ni][r] + ba[r]);
            }
        }
    }
}

// ============================ flash attention (S^T form, 128-q blocks) ======
// R5: double-buffered K/V staging with counted vmcnt — kills the exposed DMA
// latency that R4's stage-then-drain loop ate every kv-tile (MfmaUtil 22 +
// VALUBusy 42 = 64%, ~36% stall). Same discipline as gemm_body_pipe:
//   barrier (old readers of buf^1 retired) -> stage(t+1 -> buf^1) ->
//   vmcnt(4) (buf's 4 loads done, new 4 stay in flight) -> barrier -> compute.
// Tail iter: vmcnt(0). WAR: stage targets buffer whose reads completed before
// the top barrier. RAW: counted wait + barrier, per-wave loads published.
// LDS: K 2x8KB + V 2x8KB + P 18.4KB = 50.4KB -> 3 blocks/CU.
__global__ __launch_bounds__(256) void attn_k(
    const bf16_t* __restrict__ Qb, const bf16_t* __restrict__ Kb,
    const bf16_t* __restrict__ VTb, bf16_t* __restrict__ Ob)
{
    __shared__ bf16_t Kl[2][64 * 64];  // [buf][kv][d], swizzled
    __shared__ bf16_t Vl[2][64 * 64];  // [buf][d][kv], swizzled
    __shared__ bf16_t Pl[4][32 * 72];  // per-wave P[q][kv], stride 72

    const int tid = threadIdx.x;
    const int w = tid >> 6, lane = tid & 63;
    const int l15 = lane & 15, quad = lane >> 4;
    const int idx = blockIdx.x;
    const int qt = 15 - (idx >> 6);    // longest first
    const int bh = idx & 63;
    const int b = bh >> 4, h = bh & 15;
    const int q0 = qt * 128;

    const bf16_t* Qp = Qb + (size_t)bh * 2048 * 64;
    const bf16_t* Kp = Kb + (size_t)bh * 2048 * 64;
    const bf16_t* Vp = VTb + (size_t)bh * 64 * 2048;

    const int srow = w * 16 + (lane >> 3);
    const int scol = ((lane & 7) ^ ((lane >> 3) & 7)) * 8;
    const int rc0 = (quad ^ (l15 & 7)) * 8;
    const int rc1 = ((quad + 4) ^ (l15 & 7)) * 8;

    // Q as B-frag: wave w owns q rows q0 + w*32 + g*16 + l15, g=0,1 (d-contig)
    bf16x8 aq[2][2];
    #pragma unroll
    for (int g = 0; g < 2; g++) {
        const int qrow = q0 + w * 32 + g * 16 + l15;
        aq[g][0] = *(const bf16x8*)(Qp + (size_t)qrow * 64 + quad * 8);
        aq[g][1] = *(const bf16x8*)(Qp + (size_t)qrow * 64 + 32 + quad * 8);
    }

    bf16x8 vone;
    #pragma unroll
    for (int j = 0; j < 8; j++) vone[j] = (bf16_t)1.0f;

    f32x4 o[2][4];   // O^T per group: col(l15)=q, row(quad*4+r)=d within ni
    #pragma unroll
    for (int g = 0; g < 2; g++)
        #pragma unroll
        for (int ni = 0; ni < 4; ni++) o[g][ni] = (f32x4){0.f, 0.f, 0.f, 0.f};
    f32x4 lacc[2];
    lacc[0] = (f32x4){0.f, 0.f, 0.f, 0.f};
    lacc[1] = (f32x4){0.f, 0.f, 0.f, 0.f};

    const int nkv = (q0 >> 6) + 2;     // kv-tiles: kv0 = 0..q0+64 step 64

    auto stage = [&](int kvt, int buf) {
        const int kv0 = kvt << 6;
        gld_lds16(Kp + (size_t)(kv0 + srow) * 64 + scol, Kl[buf] + (w * 16) * 64);
        gld_lds16(Kp + (size_t)(kv0 + srow + 8) * 64 + scol, Kl[buf] + (w * 16 + 8) * 64);
        gld_lds16(Vp + (size_t)srow * 2048 + kv0 + scol, Vl[buf] + (w * 16) * 64);
        gld_lds16(Vp + (size_t)(srow + 8) * 2048 + kv0 + scol, Vl[buf] + (w * 16 + 8) * 64);
    };

    stage(0, 0);    // prologue: tile 0 in flight

    for (int t = 0; t < nkv; ++t) {
        const int buf = t & 1;
        const int kv0 = t << 6;
        __builtin_amdgcn_s_barrier();      // all reads of buf^1 (iter t-1) retired
        if (t + 1 < nkv) {
            stage(t + 1, buf ^ 1);
            asm volatile("s_waitcnt vmcnt(4)" ::: "memory");  // my buf loads done
        } else {
            asm volatile("s_waitcnt vmcnt(0)" ::: "memory");  // tail drain
        }
        __builtin_amdgcn_s_barrier();      // buf staged for all waves

        const bf16_t* Kb_ = Kl[buf];
        const bf16_t* Vb_ = Vl[buf];

        // K and V fragments read ONCE, reused for both q-groups
        bf16x8 ak[4][2], bv[4][2];
        #pragma unroll
        for (int ni = 0; ni < 4; ni++) {
            ak[ni][0] = *(const bf16x8*)(Kb_ + (ni * 16 + l15) * 64 + rc0);
            ak[ni][1] = *(const bf16x8*)(Kb_ + (ni * 16 + l15) * 64 + rc1);
        }
        #pragma unroll
        for (int ni = 0; ni < 4; ni++) {
            bv[ni][0] = *(const bf16x8*)(Vb_ + (ni * 16 + l15) * 64 + rc0);
            bv[ni][1] = *(const bf16x8*)(Vb_ + (ni * 16 + l15) * 64 + rc1);
        }

        #pragma unroll
        for (int g = 0; g < 2; g++) {
            const int qloc = w * 32 + g * 16 + l15;
            // S^T chunk ni: rows kv = kv0+ni*16+quad*4+r, cols q (group g)
            f32x4 sv[4];
            #pragma unroll
            for (int ni = 0; ni < 4; ni++) {
                f32x4 z = (f32x4){0.f, 0.f, 0.f, 0.f};
                z = __builtin_amdgcn_mfma_f32_16x16x32_bf16(ak[ni][0], aq[g][0], z, 0, 0, 0);
                z = __builtin_amdgcn_mfma_f32_16x16x32_bf16(ak[ni][1], aq[g][1], z, 0, 0, 0);
                sv[ni] = z;
            }

            if (kv0 >= q0) {  // causal mask on the last two tiles: kv > q
                const int koff = kv0 - q0;
                #pragma unroll
                for (int ni = 0; ni < 4; ni++)
                    #pragma unroll
                    for (int r = 0; r < 4; r++)
                        if (koff + ni * 16 + quad * 4 + r > qloc) sv[ni][r] = -INFINITY;
            }

            // p = exp2(s), pack 4 kv-adjacent -> one 8B LDS write per chunk
            #pragma unroll
            for (int ni = 0; ni < 4; ni++) {
                union { bf16_t bvv[4]; uint2 u; } pk;
                #pragma unroll
                for (int r = 0; r < 4; r++) pk.bvv[r] = (bf16_t)fexp2(sv[ni][r]);
                *(uint2*)(&Pl[w][(g * 16 + l15) * 72 + ni * 16 + quad * 4]) = pk.u;
            }
            // no barrier: Pl[w] wave-private, same-wave DS ops ordered

            // P as B-frag: rows q=l15 (group g), kv-contig
            bf16x8 pa0 = *(const bf16x8*)(&Pl[w][(g * 16 + l15) * 72 + quad * 8]);
            bf16x8 pa1 = *(const bf16x8*)(&Pl[w][(g * 16 + l15) * 72 + 32 + quad * 8]);
            #pragma unroll
            for (int ni = 0; ni < 4; ni++) {
                o[g][ni] = __builtin_amdgcn_mfma_f32_16x16x32_bf16(bv[ni][0], pa0, o[g][ni], 0, 0, 0);
                o[g][ni] = __builtin_amdgcn_mfma_f32_16x16x32_bf16(bv[ni][1], pa1, o[g][ni], 0, 0, 0);
            }
            // row-sum: ones x P -> every reg holds sum_kv P[q=l15][kv]
            lacc[g] = __builtin_amdgcn_mfma_f32_16x16x32_bf16(vone, pa0, lacc[g], 0, 0, 0);
            lacc[g] = __builtin_amdgcn_mfma_f32_16x16x32_bf16(vone, pa1, lacc[g], 0, 0, 0);
        }
    }

    #pragma unroll
    for (int g = 0; g < 2; g++) {
        const float inv = 1.0f / lacc[g][0];
        const int s = q0 + w * 32 + g * 16 + l15;
        bf16_t* obase = Ob + ((size_t)b * 2048 + s) * 1024 + h * 64;
        #pragma unroll
        for (int ni = 0; ni < 4; ni++) {
            union { bf16_t bvv[4]; uint2 u; } u;
            #pragma unroll
            for (int r = 0; r < 4; r++) u.bvv[r] = (bf16_t)(o[g][ni][r] * inv);
            *(uint2*)(obase + ni * 16 + quad * 4) = u.u;
        }
    }
}

// ============== GEMM2: output projection (A=Wo, B=O) — R2 body ==============
// grid (32,8) = 256 blocks = exactly 1 round of 256 CUs.
__global__ __launch_bounds__(512) void gemm_out_k(
    const bf16_t* __restrict__ O, const bf16_t* __restrict__ WT,
    const float* __restrict__ bias, float* __restrict__ out)
{
    __shared__ bf16_t Al[3 * 128 * 64];   // 48 KB
    __shared__ bf16_t Bl[3 * 256 * 64];   // 96 KB
    const int tid = threadIdx.x;
    const int lane = tid & 63, w = tid >> 6;
    const int l15 = lane & 15, quad = lane >> 4;
    const int wm = w >> 2, wn = w & 3;
    const int n0 = blockIdx.x * 256;   // token rows
    const int m0 = blockIdx.y * 128;   // out cols

    f32x4 acc[4][4];
    #pragma unroll
    for (int mi = 0; mi < 4; mi++)
        #pragma unroll
        for (int ni = 0; ni < 4; ni++) acc[mi][ni] = (f32x4){0.f, 0.f, 0.f, 0.f};

    gemm_body_pipe(WT, O, Al, Bl, acc, m0, n0);

    #pragma unroll
    for (int mi = 0; mi < 4; mi++) {
        const int mbase = m0 + wm * 64 + mi * 16 + quad * 4;
        const float4 bia = *(const float4*)(bias + mbase);
        #pragma unroll
        for (int ni = 0; ni < 4; ni++) {
            const int n = n0 + wn * 64 + ni * 16 + l15;
            float4 v;
            v.x = acc[mi][ni][0] + bia.x;
            v.y = acc[mi][ni][1] + bia.y;
            v.z = acc[mi][ni][2] + bia.z;
            v.w = acc[mi][ni][3] + bia.w;
            *(float4*)(out + (size_t)n * 1024 + mbase) = v;
        }
    }
}

// ============================ launcher ============================

extern "C" void kernel_launch(void* const* d_in, const int* in_sizes, int n_in,
                              void* d_out, int out_size, void* d_ws, size_t ws_size,
                              hipStream_t stream) {
    const float* x     = (const float*)d_in[0];
    const float* W_qkv = (const float*)d_in[1];
    const float* b_qkv = (const float*)d_in[2];
    const float* W_o   = (const float*)d_in[3];
    const float* b_o   = (const float*)d_in[4];
    float* out = (float*)d_out;

    char* ws = (char*)d_ws;
    size_t off = 0;
    auto alloc = [&](size_t bytes) -> void* {
        void* p = ws + off;
        off += (bytes + 255) & ~(size_t)255;
        return p;
    };
    bf16_t* xb    = (bf16_t*)alloc((size_t)8192 * 1024 * 2);
    bf16_t* wqkvT = (bf16_t*)alloc((size_t)3072 * 1024 * 2);
    bf16_t* woT   = (bf16_t*)alloc((size_t)1024 * 1024 * 2);
    bf16_t* Qb    = (bf16_t*)alloc((size_t)8192 * 1024 * 2);
    bf16_t* Kb    = (bf16_t*)alloc((size_t)8192 * 1024 * 2);
    bf16_t* VTb   = (bf16_t*)alloc((size_t)8192 * 1024 * 2);
    bf16_t* Ob    = xb;  // xb dead after gemm_qkv_k

    prep_k<<<12288, 256, 0, stream>>>(x, xb, W_qkv, wqkvT, W_o, woT);
    gemm_qkv_k<<<dim3(32, 24), 512, 0, stream>>>(xb, wqkvT, b_qkv, Qb, Kb, VTb);
    attn_k<<<1024, 256, 0, stream>>>(Qb, Kb, VTb, Ob);
    gemm_out_k<<<dim3(32, 8), 512, 0, stream>>>(Ob, woT, b_o, out);
}

// Round 6
// 242.016 us; speedup vs baseline: 1.0147x; 1.0147x over previous
//
#include <hip/hip_runtime.h>
#include <stdint.h>

typedef __bf16 bf16_t;
typedef __bf16 bf16x8 __attribute__((ext_vector_type(8)));
typedef float f32x4 __attribute__((ext_vector_type(4)));

#define LOG2E 1.44269504088896340736f

__device__ __forceinline__ float fexp2(float x) {
#if __has_builtin(__builtin_amdgcn_exp2f)
    return __builtin_amdgcn_exp2f(x);   // bare v_exp_f32
#else
    return exp2f(x);
#endif
}

// ---- async global->LDS, 16B per lane. LDS dest = wave-uniform base + lane*16.
__device__ __forceinline__ void gld_lds16(const bf16_t* g, bf16_t* l) {
    __builtin_amdgcn_global_load_lds(
        (__attribute__((address_space(1))) void*)(bf16_t*)g,
        (__attribute__((address_space(3))) void*)l,
        16, 0, 0);
}

// ============================ fused prep kernel (R6) ========================
// R5 accounting: qkv 70 + attn ~70 + out ~24 = 165 of 245 us; prep (12288
// near-empty blocks, scalar 2B transpose stores) is the only unmeasured
// kernel. R6: 3072 meaty blocks.
//  blocks [0,2048):   x f32->bf16, 4 x float4 per thread (8,388,608 elems)
//  blocks [2048,2816): W_qkv^T, 4 tiles of 32x32 per block, packed 8B stores
//  blocks [2816,3072): W_o^T, same
__global__ __launch_bounds__(256) void prep_k(
    const float* __restrict__ x, bf16_t* __restrict__ xb,
    const float* __restrict__ Wqkv, bf16_t* __restrict__ wqkvT,
    const float* __restrict__ Wo, bf16_t* __restrict__ woT)
{
    const int tid = threadIdx.x;
    int blk = blockIdx.x;
    if (blk < 2048) {
        const size_t base = (size_t)blk * 4096 + tid * 4;
        #pragma unroll
        for (int it = 0; it < 4; ++it) {
            const size_t i = base + (size_t)it * 1024;
            float4 v = *(const float4*)(x + i);
            union { bf16_t b[4]; uint2 u; } u;
            u.b[0] = (bf16_t)v.x; u.b[1] = (bf16_t)v.y;
            u.b[2] = (bf16_t)v.z; u.b[3] = (bf16_t)v.w;
            *(uint2*)(xb + i) = u.u;
        }
        return;
    }
    __shared__ float t[32][33];
    const float* in; bf16_t* out; int C, tiles_x, ti;
    if (blk < 2816) { blk -= 2048; in = Wqkv; out = wqkvT; C = 3072; tiles_x = 96; ti = blk * 4; }
    else            { blk -= 2816; in = Wo;   out = woT;   C = 1024; tiles_x = 32; ti = blk * 4; }
    const int R = 1024;
    const int tx = tid & 31, ty = tid >> 5;
    const int oc = tid >> 3, rg = (tid & 7) * 4;   // store mapping: 32 cols x 8 quads
    for (int tt = 0; tt < 4; ++tt, ++ti) {
        const int bx = ti % tiles_x, by = ti / tiles_x;
        const int c0 = bx * 32, r0 = by * 32;
        __syncthreads();   // protect LDS reuse across tiles (no-op on tt=0)
        #pragma unroll
        for (int j = 0; j < 32; j += 8)
            t[ty + j][tx] = in[(size_t)(r0 + ty + j) * C + c0 + tx];
        __syncthreads();
        // out[(c0+oc)][r0+rg..rg+3] = t[rg..rg+3][oc], one 8B store per lane
        union { bf16_t b[4]; uint2 u; } u;
        u.b[0] = (bf16_t)t[rg][oc];
        u.b[1] = (bf16_t)t[rg + 1][oc];
        u.b[2] = (bf16_t)t[rg + 2][oc];
        u.b[3] = (bf16_t)t[rg + 3][oc];
        *(uint2*)(out + (size_t)(c0 + oc) * R + r0 + rg) = u.u;
    }
}

// ================= R2-proven fine-phase pipelined GEMM body =================
// C[128x256] = A[m0:+128,:1024] * B[n0:+256,:1024]^T (row-major, k-contig).
// 512 thr / 8 waves, 2M x 4N, per-wave 64x64. BK=64; K=1024 -> 16 K-tiles.
// 3 LDS slots x (A 16KB + B 32KB) = 144 KB; prefetch distance 2 K-tiles.
// Per K-tile: 2 phases. vmcnt(6) counted wait, never 0 mid-loop.
__device__ __forceinline__ void gemm_body_pipe(
    const bf16_t* __restrict__ A, const bf16_t* __restrict__ Bt,
    bf16_t* Al, bf16_t* Bl, f32x4 (&acc)[4][4], int m0, int n0)
{
    const int tid = threadIdx.x;
    const int w = tid >> 6, lane = tid & 63;
    const int l15 = lane & 15, quad = lane >> 4;
    const int wm = w >> 2, wn = w & 3;

    const int srow = lane >> 3;                 // 0..7 within an 8-row group
    const int scg = ((lane & 7) ^ srow) * 8;    // pre-swizzled global chunk
    const bf16_t* Ag = A  + (size_t)(m0 + w * 16 + srow) * 1024 + scg;
    const bf16_t* Bg = Bt + (size_t)(n0 + w * 32 + srow) * 1024 + scg;

    const int rc0 = (quad ^ (l15 & 7)) * 8;
    const int rc1 = ((quad + 4) ^ (l15 & 7)) * 8;

    auto stage0 = [&](int kt, int ss) {   // A j0, A j1, B j0
        gld_lds16(Ag + kt * 64,                       Al + ss * 8192  + (w * 16) * 64);
        gld_lds16(Ag + kt * 64 + (size_t)8 * 1024,    Al + ss * 8192  + (w * 16 + 8) * 64);
        gld_lds16(Bg + kt * 64,                       Bl + ss * 16384 + (w * 32) * 64);
    };
    auto stage1 = [&](int kt, int ss) {   // B j1, B j2, B j3
        gld_lds16(Bg + kt * 64 + (size_t)8 * 1024,    Bl + ss * 16384 + (w * 32 + 8) * 64);
        gld_lds16(Bg + kt * 64 + (size_t)16 * 1024,   Bl + ss * 16384 + (w * 32 + 16) * 64);
        gld_lds16(Bg + kt * 64 + (size_t)24 * 1024,   Bl + ss * 16384 + (w * 32 + 24) * 64);
    };

    stage0(0, 0); stage1(0, 0);
    stage0(1, 1); stage1(1, 1);
    asm volatile("s_waitcnt vmcnt(6)" ::: "memory");
    __builtin_amdgcn_s_barrier();

    int cs = 0, ss = 2;
    for (int t = 0; t < 16; ++t) {
        const bf16_t* Ab = Al + cs * 8192;
        const bf16_t* Bb = Bl + cs * 16384;
        {
            bf16x8 af[4], bfr[4];
            #pragma unroll
            for (int mi = 0; mi < 4; mi++)
                af[mi] = *(const bf16x8*)(Ab + (wm * 64 + mi * 16 + l15) * 64 + rc0);
            #pragma unroll
            for (int ni = 0; ni < 4; ni++)
                bfr[ni] = *(const bf16x8*)(Bb + (wn * 64 + ni * 16 + l15) * 64 + rc0);
            if (t < 14) stage0(t + 2, ss);
            __builtin_amdgcn_s_barrier();
            __builtin_amdgcn_s_setprio(1);
            #pragma unroll
            for (int mi = 0; mi < 4; mi++)
                #pragma unroll
                for (int ni = 0; ni < 4; ni++)
                    acc[mi][ni] = __builtin_amdgcn_mfma_f32_16x16x32_bf16(
                        af[mi], bfr[ni], acc[mi][ni], 0, 0, 0);
            __builtin_amdgcn_s_setprio(0);
            __builtin_amdgcn_s_barrier();
        }
        {
            bf16x8 af[4], bfr[4];
            #pragma unroll
            for (int mi = 0; mi < 4; mi++)
                af[mi] = *(const bf16x8*)(Ab + (wm * 64 + mi * 16 + l15) * 64 + rc1);
            #pragma unroll
            for (int ni = 0; ni < 4; ni++)
                bfr[ni] = *(const bf16x8*)(Bb + (wn * 64 + ni * 16 + l15) * 64 + rc1);
            if (t < 14) {
                stage1(t + 2, ss);
                asm volatile("s_waitcnt vmcnt(6)" ::: "memory");
            } else if (t == 14) {
                asm volatile("s_waitcnt vmcnt(0)" ::: "memory");
            }
            __builtin_amdgcn_s_barrier();
            __builtin_amdgcn_s_setprio(1);
            #pragma unroll
            for (int mi = 0; mi < 4; mi++)
                #pragma unroll
                for (int ni = 0; ni < 4; ni++)
                    acc[mi][ni] = __builtin_amdgcn_mfma_f32_16x16x32_bf16(
                        af[mi], bfr[ni], acc[mi][ni], 0, 0, 0);
            __builtin_amdgcn_s_setprio(0);
            __builtin_amdgcn_s_barrier();
        }
        cs = (cs == 2) ? 0 : cs + 1;
        ss = (ss == 2) ? 0 : ss + 1;
    }
}

// ============================ GEMM1: qkv projection (A=W, B=x) ============
// grid (32, 24) = 768 blocks. R2-proven version (72.5 us).
__global__ __launch_bounds__(512) void gemm_qkv_k(
    const bf16_t* __restrict__ X, const bf16_t* __restrict__ WT,
    const float* __restrict__ bias,
    bf16_t* __restrict__ Qb, bf16_t* __restrict__ Kb, bf16_t* __restrict__ VTb)
{
    __shared__ bf16_t Al[3 * 128 * 64];   // 48 KB
    __shared__ bf16_t Bl[3 * 256 * 64];   // 96 KB
    const int tid = threadIdx.x;
    const int lane = tid & 63, w = tid >> 6;
    const int l15 = lane & 15, quad = lane >> 4;
    const int wm = w >> 2, wn = w & 3;
    const int n0 = blockIdx.x * 256;   // token rows
    const int m0 = blockIdx.y * 128;   // weight cols

    f32x4 acc[4][4];
    #pragma unroll
    for (int mi = 0; mi < 4; mi++)
        #pragma unroll
        for (int ni = 0; ni < 4; ni++) acc[mi][ni] = (f32x4){0.f, 0.f, 0.f, 0.f};

    gemm_body_pipe(WT, X, Al, Bl, acc, m0, n0);

    const float QSCALE = 0.125f * LOG2E;
    const int region = m0 >> 10;  // 0:Q 1:K 2:V (uniform per block; 128 | 1024)
    #pragma unroll
    for (int mi = 0; mi < 4; mi++) {
        const int mbase = m0 + wm * 64 + mi * 16 + quad * 4;
        const float4 bia = *(const float4*)(bias + mbase);
        const float ba[4] = {bia.x, bia.y, bia.z, bia.w};
        const int col = mbase & 1023;
        const int h = col >> 6, dbase = col & 63;
        #pragma unroll
        for (int ni = 0; ni < 4; ni++) {
            const int n = n0 + wn * 64 + ni * 16 + l15;
            const int b = n >> 11, s = n & 2047;
            if (region == 0) {
                union { bf16_t bv[4]; uint2 u; } u;
                #pragma unroll
                for (int r = 0; r < 4; r++)
                    u.bv[r] = (bf16_t)((acc[mi][ni][r] + ba[r]) * QSCALE);
                *(uint2*)(Qb + (((size_t)b * 16 + h) * 2048 + s) * 64 + dbase) = u.u;
            } else if (region == 1) {
                union { bf16_t bv[4]; uint2 u; } u;
                #pragma unroll
                for (int r = 0; r < 4; r++)
                    u.bv[r] = (bf16_t)(acc[mi][ni][r] + ba[r]);
                *(uint2*)(Kb + (((size_t)b * 16 + h) * 2048 + s) * 64 + dbase) = u.u;
            } else {
                bf16_t* dst = VTb + (((size_t)b * 16 + h) * 64 + dbase) * 2048 + s;
                #pragma unroll
                for (int r = 0; r < 4; r++)
                    dst[(size_t)r * 2048] = (bf16_t)(acc[mi][ni][r] + ba[r]);
            }
        }
    }
}

// ============================ flash attention (S^T form, 128-q blocks) ======
// R5-proven: double-buffered K/V staging with counted vmcnt.
//   barrier (old readers of buf^1 retired) -> stage(t+1 -> buf^1) ->
//   vmcnt(4) (buf's 4 loads done, new 4 stay in flight) -> barrier -> compute.
// LDS: K 2x8KB + V 2x8KB + P 18.4KB = 50.4KB.
__global__ __launch_bounds__(256) void attn_k(
    const bf16_t* __restrict__ Qb, const bf16_t* __restrict__ Kb,
    const bf16_t* __restrict__ VTb, bf16_t* __restrict__ Ob)
{
    __shared__ bf16_t Kl[2][64 * 64];  // [buf][kv][d], swizzled
    __shared__ bf16_t Vl[2][64 * 64];  // [buf][d][kv], swizzled
    __shared__ bf16_t Pl[4][32 * 72];  // per-wave P[q][kv], stride 72

    const int tid = threadIdx.x;
    const int w = tid >> 6, lane = tid & 63;
    const int l15 = lane & 15, quad = lane >> 4;
    const int idx = blockIdx.x;
    const int qt = 15 - (idx >> 6);    // longest first
    const int bh = idx & 63;
    const int b = bh >> 4, h = bh & 15;
    const int q0 = qt * 128;

    const bf16_t* Qp = Qb + (size_t)bh * 2048 * 64;
    const bf16_t* Kp = Kb + (size_t)bh * 2048 * 64;
    const bf16_t* Vp = VTb + (size_t)bh * 64 * 2048;

    const int srow = w * 16 + (lane >> 3);
    const int scol = ((lane & 7) ^ ((lane >> 3) & 7)) * 8;
    const int rc0 = (quad ^ (l15 & 7)) * 8;
    const int rc1 = ((quad + 4) ^ (l15 & 7)) * 8;

    // Q as B-frag: wave w owns q rows q0 + w*32 + g*16 + l15, g=0,1 (d-contig)
    bf16x8 aq[2][2];
    #pragma unroll
    for (int g = 0; g < 2; g++) {
        const int qrow = q0 + w * 32 + g * 16 + l15;
        aq[g][0] = *(const bf16x8*)(Qp + (size_t)qrow * 64 + quad * 8);
        aq[g][1] = *(const bf16x8*)(Qp + (size_t)qrow * 64 + 32 + quad * 8);
    }

    bf16x8 vone;
    #pragma unroll
    for (int j = 0; j < 8; j++) vone[j] = (bf16_t)1.0f;

    f32x4 o[2][4];   // O^T per group: col(l15)=q, row(quad*4+r)=d within ni
    #pragma unroll
    for (int g = 0; g < 2; g++)
        #pragma unroll
        for (int ni = 0; ni < 4; ni++) o[g][ni] = (f32x4){0.f, 0.f, 0.f, 0.f};
    f32x4 lacc[2];
    lacc[0] = (f32x4){0.f, 0.f, 0.f, 0.f};
    lacc[1] = (f32x4){0.f, 0.f, 0.f, 0.f};

    const int nkv = (q0 >> 6) + 2;     // kv-tiles: kv0 = 0..q0+64 step 64

    auto stage = [&](int kvt, int buf) {
        const int kv0 = kvt << 6;
        gld_lds16(Kp + (size_t)(kv0 + srow) * 64 + scol, Kl[buf] + (w * 16) * 64);
        gld_lds16(Kp + (size_t)(kv0 + srow + 8) * 64 + scol, Kl[buf] + (w * 16 + 8) * 64);
        gld_lds16(Vp + (size_t)srow * 2048 + kv0 + scol, Vl[buf] + (w * 16) * 64);
        gld_lds16(Vp + (size_t)(srow + 8) * 2048 + kv0 + scol, Vl[buf] + (w * 16 + 8) * 64);
    };

    stage(0, 0);    // prologue: tile 0 in flight

    for (int t = 0; t < nkv; ++t) {
        const int buf = t & 1;
        const int kv0 = t << 6;
        __builtin_amdgcn_s_barrier();      // all reads of buf^1 (iter t-1) retired
        if (t + 1 < nkv) {
            stage(t + 1, buf ^ 1);
            asm volatile("s_waitcnt vmcnt(4)" ::: "memory");  // my buf loads done
        } else {
            asm volatile("s_waitcnt vmcnt(0)" ::: "memory");  // tail drain
        }
        __builtin_amdgcn_s_barrier();      // buf staged for all waves

        const bf16_t* Kb_ = Kl[buf];
        const bf16_t* Vb_ = Vl[buf];

        // K and V fragments read ONCE, reused for both q-groups
        bf16x8 ak[4][2], bv[4][2];
        #pragma unroll
        for (int ni = 0; ni < 4; ni++) {
            ak[ni][0] = *(const bf16x8*)(Kb_ + (ni * 16 + l15) * 64 + rc0);
            ak[ni][1] = *(const bf16x8*)(Kb_ + (ni * 16 + l15) * 64 + rc1);
        }
        #pragma unroll
        for (int ni = 0; ni < 4; ni++) {
            bv[ni][0] = *(const bf16x8*)(Vb_ + (ni * 16 + l15) * 64 + rc0);
            bv[ni][1] = *(const bf16x8*)(Vb_ + (ni * 16 + l15) * 64 + rc1);
        }

        #pragma unroll
        for (int g = 0; g < 2; g++) {
            const int qloc = w * 32 + g * 16 + l15;
            // S^T chunk ni: rows kv = kv0+ni*16+quad*4+r, cols q (group g)
            f32x4 sv[4];
            #pragma unroll
            for (int ni = 0; ni < 4; ni++) {
                f32x4 z = (f32x4){0.f, 0.f, 0.f, 0.f};
                z = __builtin_amdgcn_mfma_f32_16x16x32_bf16(ak[ni][0], aq[g][0], z, 0, 0, 0);
                z = __builtin_amdgcn_mfma_f32_16x16x32_bf16(ak[ni][1], aq[g][1], z, 0, 0, 0);
                sv[ni] = z;
            }

            if (kv0 >= q0) {  // causal mask on the last two tiles: kv > q
                const int koff = kv0 - q0;
                #pragma unroll
                for (int ni = 0; ni < 4; ni++)
                    #pragma unroll
                    for (int r = 0; r < 4; r++)
                        if (koff + ni * 16 + quad * 4 + r > qloc) sv[ni][r] = -INFINITY;
            }

            // p = exp2(s), pack 4 kv-adjacent -> one 8B LDS write per chunk
            #pragma unroll
            for (int ni = 0; ni < 4; ni++) {
                union { bf16_t bvv[4]; uint2 u; } pk;
                #pragma unroll
                for (int r = 0; r < 4; r++) pk.bvv[r] = (bf16_t)fexp2(sv[ni][r]);
                *(uint2*)(&Pl[w][(g * 16 + l15) * 72 + ni * 16 + quad * 4]) = pk.u;
            }
            // no barrier: Pl[w] wave-private, same-wave DS ops ordered

            // P as B-frag: rows q=l15 (group g), kv-contig
            bf16x8 pa0 = *(const bf16x8*)(&Pl[w][(g * 16 + l15) * 72 + quad * 8]);
            bf16x8 pa1 = *(const bf16x8*)(&Pl[w][(g * 16 + l15) * 72 + 32 + quad * 8]);
            #pragma unroll
            for (int ni = 0; ni < 4; ni++) {
                o[g][ni] = __builtin_amdgcn_mfma_f32_16x16x32_bf16(bv[ni][0], pa0, o[g][ni], 0, 0, 0);
                o[g][ni] = __builtin_amdgcn_mfma_f32_16x16x32_bf16(bv[ni][1], pa1, o[g][ni], 0, 0, 0);
            }
            // row-sum: ones x P -> every reg holds sum_kv P[q=l15][kv]
            lacc[g] = __builtin_amdgcn_mfma_f32_16x16x32_bf16(vone, pa0, lacc[g], 0, 0, 0);
            lacc[g] = __builtin_amdgcn_mfma_f32_16x16x32_bf16(vone, pa1, lacc[g], 0, 0, 0);
        }
    }

    #pragma unroll
    for (int g = 0; g < 2; g++) {
        const float inv = 1.0f / lacc[g][0];
        const int s = q0 + w * 32 + g * 16 + l15;
        bf16_t* obase = Ob + ((size_t)b * 2048 + s) * 1024 + h * 64;
        #pragma unroll
        for (int ni = 0; ni < 4; ni++) {
            union { bf16_t bvv[4]; uint2 u; } u;
            #pragma unroll
            for (int r = 0; r < 4; r++) u.bvv[r] = (bf16_t)(o[g][ni][r] * inv);
            *(uint2*)(obase + ni * 16 + quad * 4) = u.u;
        }
    }
}

// ============== GEMM2: output projection (A=Wo, B=O) — R2 body ==============
// grid (32,8) = 256 blocks = exactly 1 round of 256 CUs.
__global__ __launch_bounds__(512) void gemm_out_k(
    const bf16_t* __restrict__ O, const bf16_t* __restrict__ WT,
    const float* __restrict__ bias, float* __restrict__ out)
{
    __shared__ bf16_t Al[3 * 128 * 64];   // 48 KB
    __shared__ bf16_t Bl[3 * 256 * 64];   // 96 KB
    const int tid = threadIdx.x;
    const int lane = tid & 63, w = tid >> 6;
    const int l15 = lane & 15, quad = lane >> 4;
    const int wm = w >> 2, wn = w & 3;
    const int n0 = blockIdx.x * 256;   // token rows
    const int m0 = blockIdx.y * 128;   // out cols

    f32x4 acc[4][4];
    #pragma unroll
    for (int mi = 0; mi < 4; mi++)
        #pragma unroll
        for (int ni = 0; ni < 4; ni++) acc[mi][ni] = (f32x4){0.f, 0.f, 0.f, 0.f};

    gemm_body_pipe(WT, O, Al, Bl, acc, m0, n0);

    #pragma unroll
    for (int mi = 0; mi < 4; mi++) {
        const int mbase = m0 + wm * 64 + mi * 16 + quad * 4;
        const float4 bia = *(const float4*)(bias + mbase);
        #pragma unroll
        for (int ni = 0; ni < 4; ni++) {
            const int n = n0 + wn * 64 + ni * 16 + l15;
            float4 v;
            v.x = acc[mi][ni][0] + bia.x;
            v.y = acc[mi][ni][1] + bia.y;
            v.z = acc[mi][ni][2] + bia.z;
            v.w = acc[mi][ni][3] + bia.w;
            *(float4*)(out + (size_t)n * 1024 + mbase) = v;
        }
    }
}

// ============================ launcher ============================

extern "C" void kernel_launch(void* const* d_in, const int* in_sizes, int n_in,
                              void* d_out, int out_size, void* d_ws, size_t ws_size,
                              hipStream_t stream) {
    const float* x     = (const float*)d_in[0];
    const float* W_qkv = (const float*)d_in[1];
    const float* b_qkv = (const float*)d_in[2];
    const float* W_o   = (const float*)d_in[3];
    const float* b_o   = (const float*)d_in[4];
    float* out = (float*)d_out;

    char* ws = (char*)d_ws;
    size_t off = 0;
    auto alloc = [&](size_t bytes) -> void* {
        void* p = ws + off;
        off += (bytes + 255) & ~(size_t)255;
        return p;
    };
    bf16_t* xb    = (bf16_t*)alloc((size_t)8192 * 1024 * 2);
    bf16_t* wqkvT = (bf16_t*)alloc((size_t)3072 * 1024 * 2);
    bf16_t* woT   = (bf16_t*)alloc((size_t)1024 * 1024 * 2);
    bf16_t* Qb    = (bf16_t*)alloc((size_t)8192 * 1024 * 2);
    bf16_t* Kb    = (bf16_t*)alloc((size_t)8192 * 1024 * 2);
    bf16_t* VTb   = (bf16_t*)alloc((size_t)8192 * 1024 * 2);
    bf16_t* Ob    = xb;  // xb dead after gemm_qkv_k

    prep_k<<<3072, 256, 0, stream>>>(x, xb, W_qkv, wqkvT, W_o, woT);
    gemm_qkv_k<<<dim3(32, 24), 512, 0, stream>>>(xb, wqkvT, b_qkv, Qb, Kb, VTb);
    attn_k<<<1024, 256, 0, stream>>>(Qb, Kb, VTb, Ob);
    gemm_out_k<<<dim3(32, 8), 512, 0, stream>>>(Ob, woT, b_o, out);
}

// Round 7
// 240.091 us; speedup vs baseline: 1.0229x; 1.0080x over previous
//
#include <hip/hip_runtime.h>
#include <stdint.h>

typedef __bf16 bf16_t;
typedef __bf16 bf16x8 __attribute__((ext_vector_type(8)));
typedef float f32x4 __attribute__((ext_vector_type(4)));

#define LOG2E 1.44269504088896340736f

__device__ __forceinline__ float fexp2(float x) {
#if __has_builtin(__builtin_amdgcn_exp2f)
    return __builtin_amdgcn_exp2f(x);   // bare v_exp_f32
#else
    return exp2f(x);
#endif
}

// ---- async global->LDS, 16B per lane. LDS dest = wave-uniform base + lane*16.
__device__ __forceinline__ void gld_lds16(const bf16_t* g, bf16_t* l) {
    __builtin_amdgcn_global_load_lds(
        (__attribute__((address_space(1))) void*)(bf16_t*)g,
        (__attribute__((address_space(3))) void*)l,
        16, 0, 0);
}

// ============================ fused prep kernel (R6-proven) =================
//  blocks [0,2048):   x f32->bf16, 4 x float4 per thread (8,388,608 elems)
//  blocks [2048,2816): W_qkv^T, 4 tiles of 32x32 per block, packed 8B stores
//  blocks [2816,3072): W_o^T, same
__global__ __launch_bounds__(256) void prep_k(
    const float* __restrict__ x, bf16_t* __restrict__ xb,
    const float* __restrict__ Wqkv, bf16_t* __restrict__ wqkvT,
    const float* __restrict__ Wo, bf16_t* __restrict__ woT)
{
    const int tid = threadIdx.x;
    int blk = blockIdx.x;
    if (blk < 2048) {
        const size_t base = (size_t)blk * 4096 + tid * 4;
        #pragma unroll
        for (int it = 0; it < 4; ++it) {
            const size_t i = base + (size_t)it * 1024;
            float4 v = *(const float4*)(x + i);
            union { bf16_t b[4]; uint2 u; } u;
            u.b[0] = (bf16_t)v.x; u.b[1] = (bf16_t)v.y;
            u.b[2] = (bf16_t)v.z; u.b[3] = (bf16_t)v.w;
            *(uint2*)(xb + i) = u.u;
        }
        return;
    }
    __shared__ float t[32][33];
    const float* in; bf16_t* out; int C, tiles_x, ti;
    if (blk < 2816) { blk -= 2048; in = Wqkv; out = wqkvT; C = 3072; tiles_x = 96; ti = blk * 4; }
    else            { blk -= 2816; in = Wo;   out = woT;   C = 1024; tiles_x = 32; ti = blk * 4; }
    const int R = 1024;
    const int tx = tid & 31, ty = tid >> 5;
    const int oc = tid >> 3, rg = (tid & 7) * 4;   // store mapping: 32 cols x 8 quads
    for (int tt = 0; tt < 4; ++tt, ++ti) {
        const int bx = ti % tiles_x, by = ti / tiles_x;
        const int c0 = bx * 32, r0 = by * 32;
        __syncthreads();   // protect LDS reuse across tiles (no-op on tt=0)
        #pragma unroll
        for (int j = 0; j < 32; j += 8)
            t[ty + j][tx] = in[(size_t)(r0 + ty + j) * C + c0 + tx];
        __syncthreads();
        // out[(c0+oc)][r0+rg..rg+3] = t[rg..rg+3][oc], one 8B store per lane
        union { bf16_t b[4]; uint2 u; } u;
        u.b[0] = (bf16_t)t[rg][oc];
        u.b[1] = (bf16_t)t[rg + 1][oc];
        u.b[2] = (bf16_t)t[rg + 2][oc];
        u.b[3] = (bf16_t)t[rg + 3][oc];
        *(uint2*)(out + (size_t)(c0 + oc) * R + r0 + rg) = u.u;
    }
}

// ================= R2-proven fine-phase pipelined GEMM body =================
// C[128x256] = A[m0:+128,:1024] * B[n0:+256,:1024]^T (row-major, k-contig).
// 512 thr / 8 waves, 2M x 4N, per-wave 64x64. BK=64; K=1024 -> 16 K-tiles.
// 3 LDS slots x (A 16KB + B 32KB) = 144 KB; prefetch distance 2 K-tiles.
// Per K-tile: 2 phases. vmcnt(6) counted wait, never 0 mid-loop.
__device__ __forceinline__ void gemm_body_pipe(
    const bf16_t* __restrict__ A, const bf16_t* __restrict__ Bt,
    bf16_t* Al, bf16_t* Bl, f32x4 (&acc)[4][4], int m0, int n0)
{
    const int tid = threadIdx.x;
    const int w = tid >> 6, lane = tid & 63;
    const int l15 = lane & 15, quad = lane >> 4;
    const int wm = w >> 2, wn = w & 3;

    const int srow = lane >> 3;                 // 0..7 within an 8-row group
    const int scg = ((lane & 7) ^ srow) * 8;    // pre-swizzled global chunk
    const bf16_t* Ag = A  + (size_t)(m0 + w * 16 + srow) * 1024 + scg;
    const bf16_t* Bg = Bt + (size_t)(n0 + w * 32 + srow) * 1024 + scg;

    const int rc0 = (quad ^ (l15 & 7)) * 8;
    const int rc1 = ((quad + 4) ^ (l15 & 7)) * 8;

    auto stage0 = [&](int kt, int ss) {   // A j0, A j1, B j0
        gld_lds16(Ag + kt * 64,                       Al + ss * 8192  + (w * 16) * 64);
        gld_lds16(Ag + kt * 64 + (size_t)8 * 1024,    Al + ss * 8192  + (w * 16 + 8) * 64);
        gld_lds16(Bg + kt * 64,                       Bl + ss * 16384 + (w * 32) * 64);
    };
    auto stage1 = [&](int kt, int ss) {   // B j1, B j2, B j3
        gld_lds16(Bg + kt * 64 + (size_t)8 * 1024,    Bl + ss * 16384 + (w * 32 + 8) * 64);
        gld_lds16(Bg + kt * 64 + (size_t)16 * 1024,   Bl + ss * 16384 + (w * 32 + 16) * 64);
        gld_lds16(Bg + kt * 64 + (size_t)24 * 1024,   Bl + ss * 16384 + (w * 32 + 24) * 64);
    };

    stage0(0, 0); stage1(0, 0);
    stage0(1, 1); stage1(1, 1);
    asm volatile("s_waitcnt vmcnt(6)" ::: "memory");
    __builtin_amdgcn_s_barrier();

    int cs = 0, ss = 2;
    for (int t = 0; t < 16; ++t) {
        const bf16_t* Ab = Al + cs * 8192;
        const bf16_t* Bb = Bl + cs * 16384;
        {
            bf16x8 af[4], bfr[4];
            #pragma unroll
            for (int mi = 0; mi < 4; mi++)
                af[mi] = *(const bf16x8*)(Ab + (wm * 64 + mi * 16 + l15) * 64 + rc0);
            #pragma unroll
            for (int ni = 0; ni < 4; ni++)
                bfr[ni] = *(const bf16x8*)(Bb + (wn * 64 + ni * 16 + l15) * 64 + rc0);
            if (t < 14) stage0(t + 2, ss);
            __builtin_amdgcn_s_barrier();
            __builtin_amdgcn_s_setprio(1);
            #pragma unroll
            for (int mi = 0; mi < 4; mi++)
                #pragma unroll
                for (int ni = 0; ni < 4; ni++)
                    acc[mi][ni] = __builtin_amdgcn_mfma_f32_16x16x32_bf16(
                        af[mi], bfr[ni], acc[mi][ni], 0, 0, 0);
            __builtin_amdgcn_s_setprio(0);
            __builtin_amdgcn_s_barrier();
        }
        {
            bf16x8 af[4], bfr[4];
            #pragma unroll
            for (int mi = 0; mi < 4; mi++)
                af[mi] = *(const bf16x8*)(Ab + (wm * 64 + mi * 16 + l15) * 64 + rc1);
            #pragma unroll
            for (int ni = 0; ni < 4; ni++)
                bfr[ni] = *(const bf16x8*)(Bb + (wn * 64 + ni * 16 + l15) * 64 + rc1);
            if (t < 14) {
                stage1(t + 2, ss);
                asm volatile("s_waitcnt vmcnt(6)" ::: "memory");
            } else if (t == 14) {
                asm volatile("s_waitcnt vmcnt(0)" ::: "memory");
            }
            __builtin_amdgcn_s_barrier();
            __builtin_amdgcn_s_setprio(1);
            #pragma unroll
            for (int mi = 0; mi < 4; mi++)
                #pragma unroll
                for (int ni = 0; ni < 4; ni++)
                    acc[mi][ni] = __builtin_amdgcn_mfma_f32_16x16x32_bf16(
                        af[mi], bfr[ni], acc[mi][ni], 0, 0, 0);
            __builtin_amdgcn_s_setprio(0);
            __builtin_amdgcn_s_barrier();
        }
        cs = (cs == 2) ? 0 : cs + 1;
        ss = (ss == 2) ? 0 : ss + 1;
    }
}

// ============================ GEMM1: qkv projection (A=W, B=x) ============
// grid (32, 24) = 768 blocks. R7: XCD-chunked swizzle (T1) — wg%8 picks the
// XCD (HW round-robins by linear wg id); each XCD owns bx in [4*xcd, 4*xcd+4)
// for ALL by -> its 4 X-panels (2 MB) stay L2-resident for the whole kernel.
// 768 % 8 == 0 -> simple chunked remap is bijective.
__global__ __launch_bounds__(512) void gemm_qkv_k(
    const bf16_t* __restrict__ X, const bf16_t* __restrict__ WT,
    const float* __restrict__ bias,
    bf16_t* __restrict__ Qb, bf16_t* __restrict__ Kb, bf16_t* __restrict__ VTb)
{
    __shared__ bf16_t Al[3 * 128 * 64];   // 48 KB
    __shared__ bf16_t Bl[3 * 256 * 64];   // 96 KB
    const int tid = threadIdx.x;
    const int lane = tid & 63, w = tid >> 6;
    const int l15 = lane & 15, quad = lane >> 4;
    const int wm = w >> 2, wn = w & 3;

    const int wg = blockIdx.x + (blockIdx.y << 5);   // [0,768)
    const int xcd = wg & 7, slot = wg >> 3;          // slot in [0,96)
    const int bx = xcd * 4 + (slot & 3);             // [0,32)
    const int by = slot >> 2;                        // [0,24)
    const int n0 = bx * 256;   // token rows
    const int m0 = by * 128;   // weight cols

    f32x4 acc[4][4];
    #pragma unroll
    for (int mi = 0; mi < 4; mi++)
        #pragma unroll
        for (int ni = 0; ni < 4; ni++) acc[mi][ni] = (f32x4){0.f, 0.f, 0.f, 0.f};

    gemm_body_pipe(WT, X, Al, Bl, acc, m0, n0);

    const float QSCALE = 0.125f * LOG2E;
    const int region = m0 >> 10;  // 0:Q 1:K 2:V (uniform per block; 128 | 1024)
    #pragma unroll
    for (int mi = 0; mi < 4; mi++) {
        const int mbase = m0 + wm * 64 + mi * 16 + quad * 4;
        const float4 bia = *(const float4*)(bias + mbase);
        const float ba[4] = {bia.x, bia.y, bia.z, bia.w};
        const int col = mbase & 1023;
        const int h = col >> 6, dbase = col & 63;
        #pragma unroll
        for (int ni = 0; ni < 4; ni++) {
            const int n = n0 + wn * 64 + ni * 16 + l15;
            const int b = n >> 11, s = n & 2047;
            if (region == 0) {
                union { bf16_t bv[4]; uint2 u; } u;
                #pragma unroll
                for (int r = 0; r < 4; r++)
                    u.bv[r] = (bf16_t)((acc[mi][ni][r] + ba[r]) * QSCALE);
                *(uint2*)(Qb + (((size_t)b * 16 + h) * 2048 + s) * 64 + dbase) = u.u;
            } else if (region == 1) {
                union { bf16_t bv[4]; uint2 u; } u;
                #pragma unroll
                for (int r = 0; r < 4; r++)
                    u.bv[r] = (bf16_t)(acc[mi][ni][r] + ba[r]);
                *(uint2*)(Kb + (((size_t)b * 16 + h) * 2048 + s) * 64 + dbase) = u.u;
            } else {
                bf16_t* dst = VTb + (((size_t)b * 16 + h) * 64 + dbase) * 2048 + s;
                #pragma unroll
                for (int r = 0; r < 4; r++)
                    dst[(size_t)r * 2048] = (bf16_t)(acc[mi][ni][r] + ba[r]);
            }
        }
    }
}

// ============================ flash attention (S^T form, 128-q blocks) ======
// R5-proven: double-buffered K/V staging with counted vmcnt. Block order
// already gives XCD affinity: blocks sharing a bh are 64 apart (64%8==0) ->
// same XCD -> K/V panels L2-resident. Unchanged this round.
__global__ __launch_bounds__(256) void attn_k(
    const bf16_t* __restrict__ Qb, const bf16_t* __restrict__ Kb,
    const bf16_t* __restrict__ VTb, bf16_t* __restrict__ Ob)
{
    __shared__ bf16_t Kl[2][64 * 64];  // [buf][kv][d], swizzled
    __shared__ bf16_t Vl[2][64 * 64];  // [buf][d][kv], swizzled
    __shared__ bf16_t Pl[4][32 * 72];  // per-wave P[q][kv], stride 72

    const int tid = threadIdx.x;
    const int w = tid >> 6, lane = tid & 63;
    const int l15 = lane & 15, quad = lane >> 4;
    const int idx = blockIdx.x;
    const int qt = 15 - (idx >> 6);    // longest first
    const int bh = idx & 63;
    const int b = bh >> 4, h = bh & 15;
    const int q0 = qt * 128;

    const bf16_t* Qp = Qb + (size_t)bh * 2048 * 64;
    const bf16_t* Kp = Kb + (size_t)bh * 2048 * 64;
    const bf16_t* Vp = VTb + (size_t)bh * 64 * 2048;

    const int srow = w * 16 + (lane >> 3);
    const int scol = ((lane & 7) ^ ((lane >> 3) & 7)) * 8;
    const int rc0 = (quad ^ (l15 & 7)) * 8;
    const int rc1 = ((quad + 4) ^ (l15 & 7)) * 8;

    // Q as B-frag: wave w owns q rows q0 + w*32 + g*16 + l15, g=0,1 (d-contig)
    bf16x8 aq[2][2];
    #pragma unroll
    for (int g = 0; g < 2; g++) {
        const int qrow = q0 + w * 32 + g * 16 + l15;
        aq[g][0] = *(const bf16x8*)(Qp + (size_t)qrow * 64 + quad * 8);
        aq[g][1] = *(const bf16x8*)(Qp + (size_t)qrow * 64 + 32 + quad * 8);
    }

    bf16x8 vone;
    #pragma unroll
    for (int j = 0; j < 8; j++) vone[j] = (bf16_t)1.0f;

    f32x4 o[2][4];   // O^T per group: col(l15)=q, row(quad*4+r)=d within ni
    #pragma unroll
    for (int g = 0; g < 2; g++)
        #pragma unroll
        for (int ni = 0; ni < 4; ni++) o[g][ni] = (f32x4){0.f, 0.f, 0.f, 0.f};
    f32x4 lacc[2];
    lacc[0] = (f32x4){0.f, 0.f, 0.f, 0.f};
    lacc[1] = (f32x4){0.f, 0.f, 0.f, 0.f};

    const int nkv = (q0 >> 6) + 2;     // kv-tiles: kv0 = 0..q0+64 step 64

    auto stage = [&](int kvt, int buf) {
        const int kv0 = kvt << 6;
        gld_lds16(Kp + (size_t)(kv0 + srow) * 64 + scol, Kl[buf] + (w * 16) * 64);
        gld_lds16(Kp + (size_t)(kv0 + srow + 8) * 64 + scol, Kl[buf] + (w * 16 + 8) * 64);
        gld_lds16(Vp + (size_t)srow * 2048 + kv0 + scol, Vl[buf] + (w * 16) * 64);
        gld_lds16(Vp + (size_t)(srow + 8) * 2048 + kv0 + scol, Vl[buf] + (w * 16 + 8) * 64);
    };

    stage(0, 0);    // prologue: tile 0 in flight

    for (int t = 0; t < nkv; ++t) {
        const int buf = t & 1;
        const int kv0 = t << 6;
        __builtin_amdgcn_s_barrier();      // all reads of buf^1 (iter t-1) retired
        if (t + 1 < nkv) {
            stage(t + 1, buf ^ 1);
            asm volatile("s_waitcnt vmcnt(4)" ::: "memory");  // my buf loads done
        } else {
            asm volatile("s_waitcnt vmcnt(0)" ::: "memory");  // tail drain
        }
        __builtin_amdgcn_s_barrier();      // buf staged for all waves

        const bf16_t* Kb_ = Kl[buf];
        const bf16_t* Vb_ = Vl[buf];

        // K and V fragments read ONCE, reused for both q-groups
        bf16x8 ak[4][2], bv[4][2];
        #pragma unroll
        for (int ni = 0; ni < 4; ni++) {
            ak[ni][0] = *(const bf16x8*)(Kb_ + (ni * 16 + l15) * 64 + rc0);
            ak[ni][1] = *(const bf16x8*)(Kb_ + (ni * 16 + l15) * 64 + rc1);
        }
        #pragma unroll
        for (int ni = 0; ni < 4; ni++) {
            bv[ni][0] = *(const bf16x8*)(Vb_ + (ni * 16 + l15) * 64 + rc0);
            bv[ni][1] = *(const bf16x8*)(Vb_ + (ni * 16 + l15) * 64 + rc1);
        }

        #pragma unroll
        for (int g = 0; g < 2; g++) {
            const int qloc = w * 32 + g * 16 + l15;
            // S^T chunk ni: rows kv = kv0+ni*16+quad*4+r, cols q (group g)
            f32x4 sv[4];
            #pragma unroll
            for (int ni = 0; ni < 4; ni++) {
                f32x4 z = (f32x4){0.f, 0.f, 0.f, 0.f};
                z = __builtin_amdgcn_mfma_f32_16x16x32_bf16(ak[ni][0], aq[g][0], z, 0, 0, 0);
                z = __builtin_amdgcn_mfma_f32_16x16x32_bf16(ak[ni][1], aq[g][1], z, 0, 0, 0);
                sv[ni] = z;
            }

            if (kv0 >= q0) {  // causal mask on the last two tiles: kv > q
                const int koff = kv0 - q0;
                #pragma unroll
                for (int ni = 0; ni < 4; ni++)
                    #pragma unroll
                    for (int r = 0; r < 4; r++)
                        if (koff + ni * 16 + quad * 4 + r > qloc) sv[ni][r] = -INFINITY;
            }

            // p = exp2(s), pack 4 kv-adjacent -> one 8B LDS write per chunk
            #pragma unroll
            for (int ni = 0; ni < 4; ni++) {
                union { bf16_t bvv[4]; uint2 u; } pk;
                #pragma unroll
                for (int r = 0; r < 4; r++) pk.bvv[r] = (bf16_t)fexp2(sv[ni][r]);
                *(uint2*)(&Pl[w][(g * 16 + l15) * 72 + ni * 16 + quad * 4]) = pk.u;
            }
            // no barrier: Pl[w] wave-private, same-wave DS ops ordered

            // P as B-frag: rows q=l15 (group g), kv-contig
            bf16x8 pa0 = *(const bf16x8*)(&Pl[w][(g * 16 + l15) * 72 + quad * 8]);
            bf16x8 pa1 = *(const bf16x8*)(&Pl[w][(g * 16 + l15) * 72 + 32 + quad * 8]);
            #pragma unroll
            for (int ni = 0; ni < 4; ni++) {
                o[g][ni] = __builtin_amdgcn_mfma_f32_16x16x32_bf16(bv[ni][0], pa0, o[g][ni], 0, 0, 0);
                o[g][ni] = __builtin_amdgcn_mfma_f32_16x16x32_bf16(bv[ni][1], pa1, o[g][ni], 0, 0, 0);
            }
            // row-sum: ones x P -> every reg holds sum_kv P[q=l15][kv]
            lacc[g] = __builtin_amdgcn_mfma_f32_16x16x32_bf16(vone, pa0, lacc[g], 0, 0, 0);
            lacc[g] = __builtin_amdgcn_mfma_f32_16x16x32_bf16(vone, pa1, lacc[g], 0, 0, 0);
        }
    }

    #pragma unroll
    for (int g = 0; g < 2; g++) {
        const float inv = 1.0f / lacc[g][0];
        const int s = q0 + w * 32 + g * 16 + l15;
        bf16_t* obase = Ob + ((size_t)b * 2048 + s) * 1024 + h * 64;
        #pragma unroll
        for (int ni = 0; ni < 4; ni++) {
            union { bf16_t bvv[4]; uint2 u; } u;
            #pragma unroll
            for (int r = 0; r < 4; r++) u.bvv[r] = (bf16_t)(o[g][ni][r] * inv);
            *(uint2*)(obase + ni * 16 + quad * 4) = u.u;
        }
    }
}

// ============== GEMM2: output projection (A=Wo, B=O) ========================
// grid (32,8) = 256 blocks. R7: XCD-chunked swizzle, 256 % 8 == 0 bijective;
// each XCD owns 4 O-panels (2 MB) L2-resident.
__global__ __launch_bounds__(512) void gemm_out_k(
    const bf16_t* __restrict__ O, const bf16_t* __restrict__ WT,
    const float* __restrict__ bias, float* __restrict__ out)
{
    __shared__ bf16_t Al[3 * 128 * 64];   // 48 KB
    __shared__ bf16_t Bl[3 * 256 * 64];   // 96 KB
    const int tid = threadIdx.x;
    const int lane = tid & 63, w = tid >> 6;
    const int l15 = lane & 15, quad = lane >> 4;
    const int wm = w >> 2, wn = w & 3;

    const int wg = blockIdx.x + (blockIdx.y << 5);   // [0,256)
    const int xcd = wg & 7, slot = wg >> 3;          // slot in [0,32)
    const int bx = xcd * 4 + (slot & 3);             // [0,32)
    const int by = slot >> 2;                        // [0,8)
    const int n0 = bx * 256;   // token rows
    const int m0 = by * 128;   // out cols

    f32x4 acc[4][4];
    #pragma unroll
    for (int mi = 0; mi < 4; mi++)
        #pragma unroll
        for (int ni = 0; ni < 4; ni++) acc[mi][ni] = (f32x4){0.f, 0.f, 0.f, 0.f};

    gemm_body_pipe(WT, O, Al, Bl, acc, m0, n0);

    #pragma unroll
    for (int mi = 0; mi < 4; mi++) {
        const int mbase = m0 + wm * 64 + mi * 16 + quad * 4;
        const float4 bia = *(const float4*)(bias + mbase);
        #pragma unroll
        for (int ni = 0; ni < 4; ni++) {
            const int n = n0 + wn * 64 + ni * 16 + l15;
            float4 v;
            v.x = acc[mi][ni][0] + bia.x;
            v.y = acc[mi][ni][1] + bia.y;
            v.z = acc[mi][ni][2] + bia.z;
            v.w = acc[mi][ni][3] + bia.w;
            *(float4*)(out + (size_t)n * 1024 + mbase) = v;
        }
    }
}

// ============================ launcher ============================

extern "C" void kernel_launch(void* const* d_in, const int* in_sizes, int n_in,
                              void* d_out, int out_size, void* d_ws, size_t ws_size,
                              hipStream_t stream) {
    const float* x     = (const float*)d_in[0];
    const float* W_qkv = (const float*)d_in[1];
    const float* b_qkv = (const float*)d_in[2];
    const float* W_o   = (const float*)d_in[3];
    const float* b_o   = (const float*)d_in[4];
    float* out = (float*)d_out;

    char* ws = (char*)d_ws;
    size_t off = 0;
    auto alloc = [&](size_t bytes) -> void* {
        void* p = ws + off;
        off += (bytes + 255) & ~(size_t)255;
        return p;
    };
    bf16_t* xb    = (bf16_t*)alloc((size_t)8192 * 1024 * 2);
    bf16_t* wqkvT = (bf16_t*)alloc((size_t)3072 * 1024 * 2);
    bf16_t* woT   = (bf16_t*)alloc((size_t)1024 * 1024 * 2);
    bf16_t* Qb    = (bf16_t*)alloc((size_t)8192 * 1024 * 2);
    bf16_t* Kb    = (bf16_t*)alloc((size_t)8192 * 1024 * 2);
    bf16_t* VTb   = (bf16_t*)alloc((size_t)8192 * 1024 * 2);
    bf16_t* Ob    = xb;  // xb dead after gemm_qkv_k

    prep_k<<<3072, 256, 0, stream>>>(x, xb, W_qkv, wqkvT, W_o, woT);
    gemm_qkv_k<<<dim3(32, 24), 512, 0, stream>>>(xb, wqkvT, b_qkv, Qb, Kb, VTb);
    attn_k<<<1024, 256, 0, stream>>>(Qb, Kb, VTb, Ob);
    gemm_out_k<<<dim3(32, 8), 512, 0, stream>>>(Ob, woT, b_o, out);
}